// Round 13
// baseline (291.905 us; speedup 1.0000x reference)
//
#include <hip/hip_runtime.h>
#include <hip/hip_bf16.h>
#include <math.h>

#define Hdim 128
#define NBq 8
#define SIq 16
#define LDP 136   // LDS row pitch (bf16 elems) for 128x128 fixup tiles
#define SKX 64    // split-K factor for xty2m

typedef __attribute__((ext_vector_type(8))) short short8x;
typedef __attribute__((ext_vector_type(8))) _Float16 half8x;
typedef __attribute__((ext_vector_type(4))) float f32x4;
typedef __attribute__((ext_vector_type(4))) unsigned short ushort4x;
typedef __attribute__((ext_vector_type(2))) _Float16 half2x;

__device__ inline unsigned short f2b(float f) {
  unsigned int u = __float_as_uint(f);
  return (unsigned short)((u + 0x7fffu + ((u >> 16) & 1u)) >> 16);   // RNE
}
__device__ inline unsigned int pack2(float lo, float hi) {
  return (unsigned int)f2b(lo) | ((unsigned int)f2b(hi) << 16);
}
__device__ inline unsigned short f2h(float f) {
  _Float16 h = (_Float16)f;
  unsigned short u;
  __builtin_memcpy(&u, &h, 2);
  return u;
}
__device__ inline half2x u2h(unsigned int u) {
  union { unsigned int u; half2x h; } v;
  v.u = u;
  return v.h;
}
__device__ inline float b2f(unsigned short u) {
  return __uint_as_float(((unsigned int)u) << 16);
}

// ---------------- fused preprocessing: gather | W-bdd transpose (f16) | dense-W transpose | dst histogram ----------------
__global__ __launch_bounds__(256) void k_pre(
    const float* __restrict__ emb, const int* __restrict__ ids, float* __restrict__ x0,
    unsigned short* __restrict__ x0h, unsigned short* __restrict__ x0t, int Nn,
    const float* __restrict__ W0, unsigned short* __restrict__ Wt0,
    const float* __restrict__ W1, unsigned short* __restrict__ Wt1, int w0elems,
    const float* __restrict__ l0, const float* __restrict__ l1,
    const float* __restrict__ Wi, const float* __restrict__ Wo, const float* __restrict__ Wz,
    unsigned short* __restrict__ l0t, unsigned short* __restrict__ l1t,
    unsigned short* __restrict__ Wit, unsigned short* __restrict__ Wot,
    unsigned short* __restrict__ Wzt,
    const int* __restrict__ dst, int* __restrict__ cnt, int E,
    int b1, int b2, int b3) {
  int bx = blockIdx.x, t = threadIdx.x;
  if (bx < b1) {
    int idx = bx * 256 + t;
    int n = idx >> 5, c4 = idx & 31;
    int s = ids[n];
    float4 v = ((const float4*)emb)[(size_t)s * 32 + c4];
    ((float4*)x0)[(size_t)n * 32 + c4] = v;
    ushort4x h;
    h.x = f2h(v.x); h.y = f2h(v.y); h.z = f2h(v.z); h.w = f2h(v.w);
    ((ushort4x*)x0h)[(size_t)n * 32 + c4] = h;
    int c0 = c4 * 4;
    x0t[(size_t)(c0 + 0) * Nn + n] = h.x;
    x0t[(size_t)(c0 + 1) * Nn + n] = h.y;
    x0t[(size_t)(c0 + 2) * Nn + n] = h.z;
    x0t[(size_t)(c0 + 3) * Nn + n] = h.w;
  } else if (bx < b2) {
    int idx = (bx - b1) * 256 + t;
    const float* W = (idx < w0elems) ? W0 : W1;
    unsigned short* Wt = (idx < w0elems) ? Wt0 : Wt1;
    int local = (idx < w0elems) ? idx : idx - w0elems;
    int rb = local >> 8, io = local & 255;
    int i = io >> 4, o = io & 15;
    Wt[(size_t)rb * 256 + o * 16 + i] = f2h(W[(size_t)rb * 256 + i * 16 + o]);   // f16 for v_dot2
  } else if (bx < b3) {
    int idx = (bx - b2) * 256 + t;
    if (idx < 65536) {
      int w = idx >> 14, local = idx & 16383;
      const float* in = (w == 0) ? l0 : (w == 1) ? l1 : (w == 2) ? Wi : Wo;
      unsigned short* out = (w == 0) ? l0t : (w == 1) ? l1t : (w == 2) ? Wit : Wot;
      int n = local >> 7, k = local & 127;
      out[local] = f2b(in[k * 128 + n]);
    } else {
      int local = idx - 65536;
      int n = local >> 7, k = local & 127;
      Wzt[local] = f2b(Wz[k * 256 + n]);
    }
  } else {
    int e = (bx - b3) * 256 + t;
    if (e < E) atomicAdd(&cnt[dst[e]], 1);
  }
}

// ---------------- dst CSR: scan / scatter-permute ----------------
__global__ __launch_bounds__(1024) void k_scan(const int* __restrict__ cnt,
                                               int* __restrict__ off,
                                               int* __restrict__ cur, int N, int E) {
  __shared__ int part[1024];
  int t = threadIdx.x;
  int ipt = N / 1024;
  int base = t * ipt;
  int loc[8];
  int s = 0;
  for (int i = 0; i < ipt; ++i) { loc[i] = s; s += cnt[base + i]; }
  part[t] = s;
  __syncthreads();
  for (int d = 1; d < 1024; d <<= 1) {
    int v = part[t];
    int add = (t >= d) ? part[t - d] : 0;
    __syncthreads();
    part[t] = v + add;
    __syncthreads();
  }
  int pre = (t == 0) ? 0 : part[t - 1];
  for (int i = 0; i < ipt; ++i) {
    int o = pre + loc[i];
    off[base + i] = o;
    cur[base + i] = o;
  }
  if (t == 0) off[N] = E;
}

__global__ void k_scatter(const int* __restrict__ src, const int* __restrict__ dst,
                          const int* __restrict__ et, const float* __restrict__ norm,
                          int* __restrict__ cur, int4* __restrict__ pedge, int E) {
  int e = blockIdx.x * blockDim.x + threadIdx.x;
  if (e >= E) return;
  int p = atomicAdd(&cur[dst[e]], 1);
  pedge[p] = make_int4(src[e], et[e], __float_as_int(norm[e]), 0);
}

// ---------------- fused edge-aggregation + MFMA GEMM ----------------
// Block (bm,bn) first computes its own 32x64 slice of the edge aggregation into
// LDS (block-diagonal W: output col group bn..bn+63 only touches b-blocks
// bn/16..bn/16+3 of W and x), then runs the MFMA GEMM with addm from LDS.
// Removes the standalone k_edge dispatches and the AGG global round-trip.
__global__ __launch_bounds__(256) void k_bgemm_e(
    const float* __restrict__ A, const unsigned short* __restrict__ Bt,
    float* __restrict__ C, const float* __restrict__ bias,
    int M, int relu, unsigned short* __restrict__ Ch,
    const unsigned short* __restrict__ xh, const unsigned short* __restrict__ Wt,
    const int* __restrict__ off, const int4* __restrict__ pedge) {
  __shared__ unsigned short Al[32][136];
  __shared__ unsigned short Bl[64][136];
  __shared__ float aggL[32][64];
  int t = threadIdx.x;
  int bm = blockIdx.x * 32, bn = blockIdx.y * 64;
  {
    int r = t >> 3, c0 = (t & 7) << 4;
    const float4* ap = (const float4*)(A + (size_t)(bm + r) * Hdim + c0);
    float4 a0 = ap[0], a1 = ap[1], a2 = ap[2], a3 = ap[3];
    uint4 p0 = { pack2(a0.x, a0.y), pack2(a0.z, a0.w), pack2(a1.x, a1.y), pack2(a1.z, a1.w) };
    uint4 p1 = { pack2(a2.x, a2.y), pack2(a2.z, a2.w), pack2(a3.x, a3.y), pack2(a3.z, a3.w) };
    *(uint4*)&Al[r][c0]     = p0;
    *(uint4*)&Al[r][c0 + 8] = p1;
  }
  {
    int n = t >> 2, k0 = (t & 3) << 5;
    const uint4* bp = (const uint4*)(Bt + (size_t)(bn + n) * Hdim + k0);
    uint4 b0 = bp[0], b1 = bp[1], b2 = bp[2], b3 = bp[3];
    *(uint4*)&Bl[n][k0]      = b0;
    *(uint4*)&Bl[n][k0 + 8]  = b1;
    *(uint4*)&Bl[n][k0 + 16] = b2;
    *(uint4*)&Bl[n][k0 + 24] = b3;
  }
  // edge phase: one wave per node, 8 passes; column = this block's half
  {
    int lane = t & 63, wavei = t >> 6;
    int gcol = bn + lane;
    int b = gcol >> 4, o = gcol & 15;
#pragma unroll 1
    for (int p = 0; p < 8; ++p) {
      int nl = p * 4 + wavei;
      int n = bm + nl;
      int j0 = off[n], j1 = off[n + 1];
      float acc = 0.f;
#pragma unroll 2
      for (int j = j0; j < j1; ++j) {
        int4 meta = pedge[j];
        int s = meta.x;
        int r = meta.y;
        float nv = __int_as_float(meta.z);
        const uint4* xp = (const uint4*)(xh + (size_t)s * Hdim + b * SIq);
        const uint4* wp = (const uint4*)(Wt + ((size_t)r * NBq + b) * 256 + o * SIq);
        uint4 xa = xp[0], xc = xp[1];
        uint4 wa = wp[0], wc = wp[1];
#if __has_builtin(__builtin_amdgcn_fdot2)
        float d0 = 0.f, d1 = 0.f;
        d0 = __builtin_amdgcn_fdot2(u2h(xa.x), u2h(wa.x), d0, false);
        d1 = __builtin_amdgcn_fdot2(u2h(xa.y), u2h(wa.y), d1, false);
        d0 = __builtin_amdgcn_fdot2(u2h(xa.z), u2h(wa.z), d0, false);
        d1 = __builtin_amdgcn_fdot2(u2h(xa.w), u2h(wa.w), d1, false);
        d0 = __builtin_amdgcn_fdot2(u2h(xc.x), u2h(wc.x), d0, false);
        d1 = __builtin_amdgcn_fdot2(u2h(xc.y), u2h(wc.y), d1, false);
        d0 = __builtin_amdgcn_fdot2(u2h(xc.z), u2h(wc.z), d0, false);
        d1 = __builtin_amdgcn_fdot2(u2h(xc.w), u2h(wc.w), d1, false);
        acc = fmaf(d0 + d1, nv, acc);
#else
        float d = 0.f;
        unsigned int xu[8] = {xa.x, xa.y, xa.z, xa.w, xc.x, xc.y, xc.z, xc.w};
        unsigned int wu[8] = {wa.x, wa.y, wa.z, wa.w, wc.x, wc.y, wc.z, wc.w};
#pragma unroll
        for (int k = 0; k < 8; ++k) {
          half2x xv = u2h(xu[k]), wv = u2h(wu[k]);
          d += (float)xv.x * (float)wv.x + (float)xv.y * (float)wv.y;
        }
        acc = fmaf(d, nv, acc);
#endif
      }
      aggL[nl][lane] = acc;
    }
  }
  __syncthreads();
  int wv = t >> 6, ln = t & 63;
  int mt = wv & 1;
  int nt0 = (wv >> 1) << 1;
  int lm = ln & 15, lk = ln >> 4;
  f32x4 acc0 = {0.f, 0.f, 0.f, 0.f}, acc1 = {0.f, 0.f, 0.f, 0.f};
#pragma unroll
  for (int ks = 0; ks < 4; ++ks) {
    short8x af = *(const short8x*)&Al[mt * 16 + lm][ks * 32 + lk * 8];
    short8x bf0 = *(const short8x*)&Bl[nt0 * 16 + lm][ks * 32 + lk * 8];
    short8x bf1 = *(const short8x*)&Bl[(nt0 + 1) * 16 + lm][ks * 32 + lk * 8];
    acc0 = __builtin_amdgcn_mfma_f32_16x16x32_bf16(af, bf0, acc0, 0, 0, 0);
    acc1 = __builtin_amdgcn_mfma_f32_16x16x32_bf16(af, bf1, acc1, 0, 0, 0);
  }
  int lc0 = nt0 * 16 + lm;
  int lc1 = lc0 + 16;
  int gcol0 = bn + lc0;
  int gcol1 = bn + lc1;
  float b0v = bias ? bias[gcol0] : 0.f;
  float b1v = bias ? bias[gcol1] : 0.f;
#pragma unroll
  for (int reg = 0; reg < 4; ++reg) {
    int lrow = mt * 16 + lk * 4 + reg;
    int grow = bm + lrow;
    size_t o0 = (size_t)grow * Hdim + gcol0;
    size_t o1 = (size_t)grow * Hdim + gcol1;
    float v0 = acc0[reg] + b0v + aggL[lrow][lc0];
    float v1 = acc1[reg] + b1v + aggL[lrow][lc1];
    if (relu) { v0 = fmaxf(v0, 0.f); v1 = fmaxf(v1, 0.f); }
    C[o0] = v0;
    C[o1] = v1;
    if (Ch) { Ch[o0] = f2h(v0); Ch[o1] = f2h(v1); }
  }
}

// ---------------- MFMA bf16 GEMM: C[M,128] = A[M,128]@B + addm + bias + relu ----------------
__global__ __launch_bounds__(256) void k_bgemm(
    const float* __restrict__ A, const unsigned short* __restrict__ Bt,
    float* __restrict__ C,
    const float* __restrict__ addm, const float* __restrict__ bias,
    int M, int Nc, int relu, unsigned short* __restrict__ Ch) {
  __shared__ unsigned short Al[32][136];
  __shared__ unsigned short Bl[64][136];
  int t = threadIdx.x;
  int bm = blockIdx.x * 32, bn = blockIdx.y * 64;
  {
    int r = t >> 3, c0 = (t & 7) << 4;
    const float4* ap = (const float4*)(A + (size_t)(bm + r) * Hdim + c0);
    float4 a0 = ap[0], a1 = ap[1], a2 = ap[2], a3 = ap[3];
    uint4 p0 = { pack2(a0.x, a0.y), pack2(a0.z, a0.w), pack2(a1.x, a1.y), pack2(a1.z, a1.w) };
    uint4 p1 = { pack2(a2.x, a2.y), pack2(a2.z, a2.w), pack2(a3.x, a3.y), pack2(a3.z, a3.w) };
    *(uint4*)&Al[r][c0]     = p0;
    *(uint4*)&Al[r][c0 + 8] = p1;
  }
  {
    int n = t >> 2, k0 = (t & 3) << 5;
    const uint4* bp = (const uint4*)(Bt + (size_t)(bn + n) * Hdim + k0);
    uint4 b0 = bp[0], b1 = bp[1], b2 = bp[2], b3 = bp[3];
    *(uint4*)&Bl[n][k0]      = b0;
    *(uint4*)&Bl[n][k0 + 8]  = b1;
    *(uint4*)&Bl[n][k0 + 16] = b2;
    *(uint4*)&Bl[n][k0 + 24] = b3;
  }
  __syncthreads();
  int wv = t >> 6, ln = t & 63;
  int mt = wv & 1;
  int nt0 = (wv >> 1) << 1;
  int lm = ln & 15, lk = ln >> 4;
  f32x4 acc0 = {0.f, 0.f, 0.f, 0.f}, acc1 = {0.f, 0.f, 0.f, 0.f};
#pragma unroll
  for (int ks = 0; ks < 4; ++ks) {
    short8x af = *(const short8x*)&Al[mt * 16 + lm][ks * 32 + lk * 8];
    short8x bf0 = *(const short8x*)&Bl[nt0 * 16 + lm][ks * 32 + lk * 8];
    short8x bf1 = *(const short8x*)&Bl[(nt0 + 1) * 16 + lm][ks * 32 + lk * 8];
    acc0 = __builtin_amdgcn_mfma_f32_16x16x32_bf16(af, bf0, acc0, 0, 0, 0);
    acc1 = __builtin_amdgcn_mfma_f32_16x16x32_bf16(af, bf1, acc1, 0, 0, 0);
  }
  int gcol0 = bn + nt0 * 16 + lm;
  int gcol1 = gcol0 + 16;
  float b0v = bias ? bias[gcol0] : 0.f;
  float b1v = bias ? bias[gcol1] : 0.f;
#pragma unroll
  for (int reg = 0; reg < 4; ++reg) {
    int grow = bm + mt * 16 + lk * 4 + reg;
    size_t o0 = (size_t)grow * Nc + gcol0;
    size_t o1 = (size_t)grow * Nc + gcol1;
    float v0 = acc0[reg] + b0v;
    float v1 = acc1[reg] + b1v;
    if (addm) { v0 += addm[o0]; v1 += addm[o1]; }
    if (relu) { v0 = fmaxf(v0, 0.f); v1 = fmaxf(v1, 0.f); }
    C[o0] = v0;
    C[o1] = v1;
    if (Ch) { Ch[o0] = f2h(v0); Ch[o1] = f2h(v1); }
  }
}

// ---------------- MFMA bf16 zml GEMM fused with reparameterization (+ f16 Z^T emit, s1/cx0 zeroing) ----------------
__global__ __launch_bounds__(256) void k_bgemm_z(
    const float* __restrict__ A, const unsigned short* __restrict__ Wzt,
    const float* __restrict__ bz, const float* __restrict__ eps,
    float* __restrict__ Z, int M, int Nn,
    unsigned short* __restrict__ Zth, float* __restrict__ gz) {
  __shared__ unsigned short Al[32][136];
  __shared__ unsigned short Bm[64][136];
  __shared__ unsigned short Bl[64][136];
  int t = threadIdx.x;
  int bm = blockIdx.x * 32, bn = blockIdx.y * 64;
  if (gz && blockIdx.x == 0 && blockIdx.y == 0 && t < 64)
    ((float4*)gz)[t] = make_float4(0.f, 0.f, 0.f, 0.f);   // s1 + cx0 (256 floats)
  {
    int r = t >> 3, c0 = (t & 7) << 4;
    const float4* ap = (const float4*)(A + (size_t)(bm + r) * Hdim + c0);
    float4 a0 = ap[0], a1 = ap[1], a2 = ap[2], a3 = ap[3];
    uint4 p0 = { pack2(a0.x, a0.y), pack2(a0.z, a0.w), pack2(a1.x, a1.y), pack2(a1.z, a1.w) };
    uint4 p1 = { pack2(a2.x, a2.y), pack2(a2.z, a2.w), pack2(a3.x, a3.y), pack2(a3.z, a3.w) };
    *(uint4*)&Al[r][c0]     = p0;
    *(uint4*)&Al[r][c0 + 8] = p1;
  }
  {
    int n = t >> 2, k0 = (t & 3) << 5;
    const uint4* mp = (const uint4*)(Wzt + (size_t)(bn + n) * Hdim + k0);
    const uint4* lp = (const uint4*)(Wzt + (size_t)(bn + 128 + n) * Hdim + k0);
    uint4 m0 = mp[0], m1 = mp[1], m2 = mp[2], m3 = mp[3];
    uint4 l0 = lp[0], l1 = lp[1], l2 = lp[2], l3 = lp[3];
    *(uint4*)&Bm[n][k0]      = m0; *(uint4*)&Bm[n][k0 + 8]  = m1;
    *(uint4*)&Bm[n][k0 + 16] = m2; *(uint4*)&Bm[n][k0 + 24] = m3;
    *(uint4*)&Bl[n][k0]      = l0; *(uint4*)&Bl[n][k0 + 8]  = l1;
    *(uint4*)&Bl[n][k0 + 16] = l2; *(uint4*)&Bl[n][k0 + 24] = l3;
  }
  __syncthreads();
  int wv = t >> 6, ln = t & 63;
  int mt = wv & 1;
  int nt0 = (wv >> 1) << 1;
  int lm = ln & 15, lk = ln >> 4;
  f32x4 am0 = {0,0,0,0}, am1 = {0,0,0,0}, al0 = {0,0,0,0}, al1 = {0,0,0,0};
#pragma unroll
  for (int ks = 0; ks < 4; ++ks) {
    short8x af = *(const short8x*)&Al[mt * 16 + lm][ks * 32 + lk * 8];
    short8x bm0 = *(const short8x*)&Bm[nt0 * 16 + lm][ks * 32 + lk * 8];
    short8x bm1 = *(const short8x*)&Bm[(nt0 + 1) * 16 + lm][ks * 32 + lk * 8];
    short8x bl0 = *(const short8x*)&Bl[nt0 * 16 + lm][ks * 32 + lk * 8];
    short8x bl1 = *(const short8x*)&Bl[(nt0 + 1) * 16 + lm][ks * 32 + lk * 8];
    am0 = __builtin_amdgcn_mfma_f32_16x16x32_bf16(af, bm0, am0, 0, 0, 0);
    am1 = __builtin_amdgcn_mfma_f32_16x16x32_bf16(af, bm1, am1, 0, 0, 0);
    al0 = __builtin_amdgcn_mfma_f32_16x16x32_bf16(af, bl0, al0, 0, 0, 0);
    al1 = __builtin_amdgcn_mfma_f32_16x16x32_bf16(af, bl1, al1, 0, 0, 0);
  }
  int gcol0 = bn + nt0 * 16 + lm;
  int gcol1 = gcol0 + 16;
  float bm0v = bz[gcol0], bm1v = bz[gcol1];
  float bl0v = bz[128 + gcol0], bl1v = bz[128 + gcol1];
#pragma unroll
  for (int reg = 0; reg < 4; ++reg) {
    int grow = bm + mt * 16 + lk * 4 + reg;
    size_t o0 = (size_t)grow * Hdim + gcol0;
    size_t o1 = (size_t)grow * Hdim + gcol1;
    float v0 = am0[reg] + bm0v + expf(al0[reg] + bl0v) * eps[o0];
    float v1 = am1[reg] + bm1v + expf(al1[reg] + bl1v) * eps[o1];
    Z[o0] = v0;
    Z[o1] = v1;
    Zth[(size_t)gcol0 * Nn + grow] = f2h(v0);
    Zth[(size_t)gcol1 * Nn + grow] = f2h(v1);
  }
}

// ---------------- MFMA f16 split-K: part[kc] = Zt-chunk^T outer products; + colsums ----------------
__global__ __launch_bounds__(256) void k_xty2m(
    const unsigned short* __restrict__ Zt, const unsigned short* __restrict__ X0t,
    float* __restrict__ part, float* __restrict__ s1, float* __restrict__ cx0, int N) {
  int kc = blockIdx.x, yt = blockIdx.y;
  int t = threadIdx.x;
  int KC = N / SKX;            // 128
  int k0 = kc * KC;
  if (yt == 4) {               // colsum blocks: s1 = colsum Z, cx0 = colsum X0
    int c = t & 127;
    const unsigned short* row = ((t >> 7) ? X0t : Zt) + (size_t)c * N + k0;
    float acc = 0.f;
    for (int i = 0; i < KC; i += 8) {
      uint4 v = *(const uint4*)(row + i);
      half2x a0 = u2h(v.x), a1 = u2h(v.y), a2 = u2h(v.z), a3 = u2h(v.w);
      acc += (float)a0.x + (float)a0.y + (float)a1.x + (float)a1.y
           + (float)a2.x + (float)a2.y + (float)a3.x + (float)a3.y;
    }
    atomicAdd(((t >> 7) ? cx0 : s1) + c, acc);
    return;
  }
  __shared__ unsigned short Asl[128][72];
  __shared__ unsigned short Bsl[64][72];
  int wv = t >> 6, ln = t & 63, lm = ln & 15, lk = ln >> 4;
  f32x4 acc[8];
#pragma unroll
  for (int i = 0; i < 8; ++i) acc[i] = (f32x4){0.f, 0.f, 0.f, 0.f};
  for (int ch = 0; ch < KC; ch += 64) {
    {
      int r = t >> 1, s = (t & 1) * 32;
      const uint4* gp = (const uint4*)(Zt + (size_t)r * N + k0 + ch + s);
      uint4 v0 = gp[0], v1 = gp[1], v2 = gp[2], v3 = gp[3];
      *(uint4*)&Asl[r][s]      = v0;
      *(uint4*)&Asl[r][s + 8]  = v1;
      *(uint4*)&Asl[r][s + 16] = v2;
      *(uint4*)&Asl[r][s + 24] = v3;
    }
    if (t < 128) {
      int n = t >> 1, s = (t & 1) * 32;
      int yn = yt * 64 + n;
      const unsigned short* Sb = (yn < 128) ? (Zt + (size_t)yn * N)
                                            : (X0t + (size_t)(yn - 128) * N);
      const uint4* gp = (const uint4*)(Sb + k0 + ch + s);
      uint4 v0 = gp[0], v1 = gp[1], v2 = gp[2], v3 = gp[3];
      *(uint4*)&Bsl[n][s]      = v0;
      *(uint4*)&Bsl[n][s + 8]  = v1;
      *(uint4*)&Bsl[n][s + 16] = v2;
      *(uint4*)&Bsl[n][s + 24] = v3;
    }
    __syncthreads();
#pragma unroll
    for (int ks = 0; ks < 2; ++ks) {
      half8x bf = *(const half8x*)&Bsl[wv * 16 + lm][ks * 32 + lk * 8];
#pragma unroll
      for (int mi = 0; mi < 8; ++mi) {
        half8x af = *(const half8x*)&Asl[mi * 16 + lm][ks * 32 + lk * 8];
        acc[mi] = __builtin_amdgcn_mfma_f32_16x16x32_f16(af, bf, acc[mi], 0, 0, 0);
      }
    }
    __syncthreads();
  }
  int gcol = yt * 64 + wv * 16 + lm;
  float* pb = part + (size_t)kc * (128 * 256) + gcol;
#pragma unroll
  for (int mi = 0; mi < 8; ++mi)
#pragma unroll
    for (int rg = 0; rg < 4; ++rg)
      pb[(size_t)(mi * 16 + lk * 4 + rg) * 256] = acc[mi][rg];
}

// ---------------- reduce split-K partials ----------------
__global__ __launch_bounds__(256) void k_red(const float* __restrict__ part,
                                             float* __restrict__ SP) {
  int idx = blockIdx.x * 256 + threadIdx.x;
  float a = 0.f;
#pragma unroll 8
  for (int s = 0; s < SKX; ++s) a += part[(size_t)s * 32768 + idx];
  SP[idx] = a;
}

// ---------------- single-block on-chip fixup (all-LDS) ----------------
__device__ inline void stage_f32(unsigned short* dst, const float* __restrict__ src,
                                 int ldF, int t) {
#pragma unroll
  for (int it = 0; it < 2; ++it) {
    int id = it * 1024 + t; int row = id >> 4, ch = id & 15;
    const float4* gp = (const float4*)(src + (size_t)row * ldF) + ch * 2;
    float4 u = gp[0], v = gp[1];
    uint4 pk = { pack2(u.x, u.y), pack2(u.z, u.w), pack2(v.x, v.y), pack2(v.z, v.w) };
    *(uint4*)&dst[row * LDP + ch * 8] = pk;
  }
}
__device__ inline void stage_b16(unsigned short* dst, const unsigned short* __restrict__ src,
                                 int t) {
#pragma unroll
  for (int it = 0; it < 2; ++it) {
    int id = it * 1024 + t; int row = id >> 4, ch = id & 15;
    *(uint4*)&dst[row * LDP + ch * 8] = ((const uint4*)(src + (size_t)row * 128))[ch];
  }
}
__device__ inline void mm128(const unsigned short* A, const unsigned short* B,
                             f32x4 (&Cc)[2][2], int wr, int wc, int lm, int lk) {
#pragma unroll
  for (int ks = 0; ks < 4; ++ks) {
    short8x af0 = *(const short8x*)&A[(wr * 32 + lm) * LDP + ks * 32 + lk * 8];
    short8x af1 = *(const short8x*)&A[(wr * 32 + 16 + lm) * LDP + ks * 32 + lk * 8];
    short8x bf0 = *(const short8x*)&B[(wc * 32 + lm) * LDP + ks * 32 + lk * 8];
    short8x bf1 = *(const short8x*)&B[(wc * 32 + 16 + lm) * LDP + ks * 32 + lk * 8];
    Cc[0][0] = __builtin_amdgcn_mfma_f32_16x16x32_bf16(af0, bf0, Cc[0][0], 0, 0, 0);
    Cc[0][1] = __builtin_amdgcn_mfma_f32_16x16x32_bf16(af0, bf1, Cc[0][1], 0, 0, 0);
    Cc[1][0] = __builtin_amdgcn_mfma_f32_16x16x32_bf16(af1, bf0, Cc[1][0], 0, 0, 0);
    Cc[1][1] = __builtin_amdgcn_mfma_f32_16x16x32_bf16(af1, bf1, Cc[1][1], 0, 0, 0);
  }
}
#define ZEROC {                                           \
  _Pragma("unroll") for (int mi = 0; mi < 2; ++mi)        \
  _Pragma("unroll") for (int ni = 0; ni < 2; ++ni)        \
    C[mi][ni] = (f32x4){0.f, 0.f, 0.f, 0.f}; }

__global__ __launch_bounds__(1024) void k_fix(
    const float* __restrict__ SP, const float* __restrict__ s1g,
    const float* __restrict__ cx0g,
    const unsigned short* __restrict__ Wit, const unsigned short* __restrict__ Wot,
    const float* __restrict__ bi, const float* __restrict__ hbi,
    const float* __restrict__ bo, const float* __restrict__ hbo,
    unsigned short* __restrict__ G12t, float* __restrict__ bvec, float Nf) {
  __shared__ unsigned short T0[128 * LDP];
  __shared__ unsigned short T1[128 * LDP];
  __shared__ unsigned short T2[128 * LDP];
  __shared__ unsigned short T3[128 * LDP];
  __shared__ float s1l[128], tl[128], s2l[128], cxl[128], bil[128], bol[128], hl[128];
  int t = threadIdx.x;
  int wv = t >> 6, ln = t & 63, lm = ln & 15, lk = ln >> 4;
  int wr = wv >> 2, wc = wv & 3;
  if (t < 128) {
    s1l[t] = s1g[t]; cxl[t] = cx0g[t]; bil[t] = bi[t]; bol[t] = bo[t]; hl[t] = hbi[t];
  }
  stage_f32(T0, SP, 256, t);     // S1
  stage_b16(T1, Wit, t);         // Wi
  __syncthreads();
  f32x4 C[2][2];
  // ph1: G1 = S1 @ Wi + s1 (x) bi + P1 ; G1 -> T2, G1^T -> T3
  ZEROC; mm128(T0, T1, C, wr, wc, lm, lk);
#pragma unroll
  for (int mi = 0; mi < 2; ++mi)
#pragma unroll
  for (int ni = 0; ni < 2; ++ni) {
    int gcol = wc * 32 + ni * 16 + lm;
    int g0 = wr * 32 + mi * 16 + lk * 4;
    ushort4x pk;
#pragma unroll
    for (int rg = 0; rg < 4; ++rg) {
      int grow = g0 + rg;
      float v = C[mi][ni][rg] + s1l[grow] * bil[gcol] + SP[(size_t)grow * 256 + 128 + gcol];
      unsigned short hv = f2b(v);
      T2[grow * LDP + gcol] = hv;
      pk[rg] = hv;
    }
    *(ushort4x*)&T3[gcol * LDP + g0] = pk;
  }
  __syncthreads();
  // ph2: tl = G1^T s1 ; s2 = tl + N*hbi
  {
    int row = t >> 3, seg = t & 7;
    const unsigned short* gr = T3 + row * LDP + seg * 16;
    float a2 = 0.f;
#pragma unroll
    for (int i = 0; i < 16; ++i) a2 += b2f(gr[i]) * s1l[seg * 16 + i];
    a2 += __shfl_xor(a2, 1);
    a2 += __shfl_xor(a2, 2);
    a2 += __shfl_xor(a2, 4);
    if (seg == 0) { tl[row] = a2; s2l[row] = a2 + Nf * hl[row]; }
  }
  __syncthreads();
  // ph3: A2 = G1^T @ S1 -> T1 ; stage P1^T -> T0
  ZEROC; mm128(T3, T0, C, wr, wc, lm, lk);
  __syncthreads();
#pragma unroll
  for (int mi = 0; mi < 2; ++mi)
#pragma unroll
  for (int ni = 0; ni < 2; ++ni) {
    int gcol = wc * 32 + ni * 16 + lm;
    int g0 = wr * 32 + mi * 16 + lk * 4;
#pragma unroll
    for (int rg = 0; rg < 4; ++rg)
      T1[(g0 + rg) * LDP + gcol] = f2b(C[mi][ni][rg]);
  }
  {
#pragma unroll
    for (int it = 0; it < 2; ++it) {
      int id = it * 1024 + t; int row = id >> 4, c0 = (id & 15) * 8;
      const float4* gp = (const float4*)(SP + (size_t)row * 256 + 128 + c0);
      float4 u = gp[0], v2 = gp[1];
      float vals[8] = {u.x, u.y, u.z, u.w, v2.x, v2.y, v2.z, v2.w};
#pragma unroll
      for (int q = 0; q < 8; ++q) T0[(c0 + q) * LDP + row] = f2b(vals[q]);
    }
  }
  __syncthreads();
  // ph4: P2 = G1^T @ P1 + hbi (x) cx0 -> T0
  ZEROC; mm128(T3, T0, C, wr, wc, lm, lk);
  __syncthreads();
#pragma unroll
  for (int mi = 0; mi < 2; ++mi)
#pragma unroll
  for (int ni = 0; ni < 2; ++ni) {
    int gcol = wc * 32 + ni * 16 + lm;
    int g0 = wr * 32 + mi * 16 + lk * 4;
#pragma unroll
    for (int rg = 0; rg < 4; ++rg) {
      int grow = g0 + rg;
      T0[grow * LDP + gcol] = f2b(C[mi][ni][rg] + hl[grow] * cxl[gcol]);
    }
  }
  __syncthreads();
  // ph5: S2 = A2 @ G1 + rank-1 terms -> T1 ; stage Wo -> T3
  ZEROC; mm128(T1, T3, C, wr, wc, lm, lk);
  __syncthreads();
#pragma unroll
  for (int mi = 0; mi < 2; ++mi)
#pragma unroll
  for (int ni = 0; ni < 2; ++ni) {
    int gcol = wc * 32 + ni * 16 + lm;
    int g0 = wr * 32 + mi * 16 + lk * 4;
#pragma unroll
    for (int rg = 0; rg < 4; ++rg) {
      int grow = g0 + rg;
      float v = C[mi][ni][rg] + tl[grow] * hl[gcol] + hl[grow] * tl[gcol]
              + Nf * hl[grow] * hl[gcol];
      T1[grow * LDP + gcol] = f2b(v);
    }
  }
  stage_b16(T3, Wot, t);
  __syncthreads();
  // ph6: G2 = S2 @ Wo + s2 (x) bo + P2 -> G2^T in T0
  ZEROC; mm128(T1, T3, C, wr, wc, lm, lk);
  float g2v[2][2][4];
#pragma unroll
  for (int mi = 0; mi < 2; ++mi)
#pragma unroll
  for (int ni = 0; ni < 2; ++ni) {
    int gcol = wc * 32 + ni * 16 + lm;
    int g0 = wr * 32 + mi * 16 + lk * 4;
#pragma unroll
    for (int rg = 0; rg < 4; ++rg) {
      int grow = g0 + rg;
      g2v[mi][ni][rg] = C[mi][ni][rg] + s2l[grow] * bol[gcol]
                      + b2f(T0[grow * LDP + gcol]);
    }
  }
  __syncthreads();
#pragma unroll
  for (int mi = 0; mi < 2; ++mi)
#pragma unroll
  for (int ni = 0; ni < 2; ++ni) {
    int gcol = wc * 32 + ni * 16 + lm;
    int g0 = wr * 32 + mi * 16 + lk * 4;
    ushort4x pk;
#pragma unroll
    for (int rg = 0; rg < 4; ++rg) pk[rg] = f2b(g2v[mi][ni][rg]);
    *(ushort4x*)&T0[gcol * LDP + g0] = pk;
  }
  __syncthreads();
  // ph8: bvec
  {
    int row = t >> 3, seg = t & 7;
    const unsigned short* gr = T0 + row * LDP + seg * 16;
    float a2 = 0.f;
#pragma unroll
    for (int i = 0; i < 16; ++i) a2 += hl[seg * 16 + i] * b2f(gr[i]);
    a2 += __shfl_xor(a2, 1);
    a2 += __shfl_xor(a2, 2);
    a2 += __shfl_xor(a2, 4);
    if (seg == 0) bvec[row] = a2 + hbo[row];
  }
  // ph7: G12 = G1 @ G2 -> G12^T in T1 -> coalesced copy out
  ZEROC; mm128(T2, T0, C, wr, wc, lm, lk);
#pragma unroll
  for (int mi = 0; mi < 2; ++mi)
#pragma unroll
  for (int ni = 0; ni < 2; ++ni) {
    int gcol = wc * 32 + ni * 16 + lm;
    int g0 = wr * 32 + mi * 16 + lk * 4;
    ushort4x pk;
#pragma unroll
    for (int rg = 0; rg < 4; ++rg) pk[rg] = f2b(C[mi][ni][rg]);
    *(ushort4x*)&T1[gcol * LDP + g0] = pk;
  }
  __syncthreads();
#pragma unroll
  for (int it = 0; it < 2; ++it) {
    int id = it * 1024 + t; int row = id >> 4, ch = (id & 15) * 8;
    *(uint4*)&G12t[row * 128 + ch] = *(uint4*)&T1[row * LDP + ch];
  }
}

extern "C" void kernel_launch(void* const* d_in, const int* in_sizes, int n_in,
                              void* d_out, int out_size, void* d_ws, size_t ws_size,
                              hipStream_t stream) {
  const int*   node_ids = (const int*)d_in[0];
  const int*   src      = (const int*)d_in[1];
  const int*   dst      = (const int*)d_in[2];
  const int*   et       = (const int*)d_in[3];
  const float* norm     = (const float*)d_in[4];
  const float* eps      = (const float*)d_in[5];
  const float* emb      = (const float*)d_in[6];
  const float* W0       = (const float*)d_in[7];
  const float* loop0    = (const float*)d_in[8];
  const float* b0       = (const float*)d_in[9];
  const float* W1       = (const float*)d_in[10];
  const float* loop1    = (const float*)d_in[11];
  const float* b1       = (const float*)d_in[12];
  const float* Wz       = (const float*)d_in[13];
  const float* bz       = (const float*)d_in[14];
  const float* Wi       = (const float*)d_in[15];
  const float* bi       = (const float*)d_in[16];
  const float* hbi      = (const float*)d_in[17];
  const float* Wo       = (const float*)d_in[18];
  const float* bo       = (const float*)d_in[19];
  const float* hbo      = (const float*)d_in[20];
  float* out = (float*)d_out;

  const int N  = in_sizes[0];   // 8192
  const int E  = in_sizes[1];   // 131072
  const int RB = in_sizes[7] / (SIq * SIq);   // NREL * NBq = 720

  char* ws = (char*)d_ws;
  const size_t MB = 1u << 20;
  const size_t KB = 1u << 10;
  float* X0   = (float*)(ws + 0 * MB);
  float* B1p  = (float*)(ws + 4 * MB);      // h1, then z
  float* B2p  = (float*)(ws + 8 * MB);      // h2 (dead before part is written)
  float* part = (float*)(ws + 8 * MB);      // overlays B2p after h2 consumed
  float* SPb  = (float*)(ws + 16 * MB);
  float* s1p  = SPb + 32768;
  float* cx0p = SPb + 32896;
  unsigned short* G12t = (unsigned short*)(ws + 16 * MB + 576 * KB);
  float* bvec = (float*)(ws + 16 * MB + 640 * KB);
  int*   offp = (int*)(ws + 17 * MB);
  int*   curp = (int*)(ws + 17 * MB + 128 * KB);
  int*   cntp = (int*)(ws + 17 * MB + 256 * KB);
  int4*  pedge = (int4*)(ws + 18 * MB);             // 2 MB
  unsigned short* Wt0 = (unsigned short*)(ws + 20 * MB);
  unsigned short* Wt1 = (unsigned short*)(ws + 20 * MB + 512 * KB);
  unsigned short* l0t = (unsigned short*)(ws + 21 * MB);
  unsigned short* l1t = (unsigned short*)(ws + 21 * MB + 64 * KB);
  unsigned short* Wit = (unsigned short*)(ws + 21 * MB + 128 * KB);
  unsigned short* Wot = (unsigned short*)(ws + 21 * MB + 192 * KB);
  unsigned short* Wzt = (unsigned short*)(ws + 21 * MB + 256 * KB);
  unsigned short* X0H = (unsigned short*)(ws + 22 * MB);   // f16 x0 row-major
  unsigned short* B1H = (unsigned short*)(ws + 24 * MB);   // f16 h1 row-major
  unsigned short* Ztc = (unsigned short*)(ws + 26 * MB);   // f16 z col-major
  unsigned short* X0t = (unsigned short*)(ws + 28 * MB);   // f16 x0 col-major

  dim3 blk(256);

  const int w0elems = RB * 256;                      // 184320
  const int gB   = (N * 32) / 256;                   // 1024
  const int wtbB = (2 * w0elems + 255) / 256;        // 1440
  const int wttB = 98304 / 256;                      // 384
  const int histB = (E + 255) / 256;                 // 512
  const int b1s = gB, b2s = gB + wtbB, b3s = gB + wtbB + wttB;
  hipMemsetAsync(cntp, 0, (size_t)N * sizeof(int), stream);
  k_pre<<<dim3(b3s + histB), blk, 0, stream>>>(
      emb, node_ids, X0, X0H, X0t, N, W0, Wt0, W1, Wt1, w0elems,
      loop0, loop1, Wi, Wo, Wz, l0t, l1t, Wit, Wot, Wzt,
      dst, cntp, E, b1s, b2s, b3s);
  k_scan<<<dim3(1), dim3(1024), 0, stream>>>(cntp, offp, curp, N, E);
  k_scatter<<<dim3((E + 255) / 256), blk, 0, stream>>>(src, dst, et, norm, curp, pedge, E);

  // layer 0: fused edge aggregation + h1 GEMM (relu, emit f16 copy)
  k_bgemm_e<<<dim3(N / 32, 2), blk, 0, stream>>>(X0, l0t, B1p, b0, N, 1, B1H,
                                                 X0H, Wt0, offp, pedge);
  // layer 1: fused edge aggregation + h2 GEMM
  k_bgemm_e<<<dim3(N / 32, 2), blk, 0, stream>>>(B1p, l1t, B2p, b1, N, 0, nullptr,
                                                 B1H, Wt1, offp, pedge);
  // z = mean + exp(log_std)*eps -> B1p, Ztc (f16 col-major); zero s1/cx0
  k_bgemm_z<<<dim3(N / 32, 2), blk, 0, stream>>>(B2p, Wzt, bz, eps, B1p, N, N, Ztc, s1p);
  // SP split-K partials + colsums
  k_xty2m<<<dim3(SKX, 5), blk, 0, stream>>>(Ztc, X0t, part, s1p, cx0p, N);
  k_red<<<dim3(128), blk, 0, stream>>>(part, SPb);
  // on-chip algebraic fixup -> G12 + bvec
  k_fix<<<dim3(1), dim3(1024), 0, stream>>>(SPb, s1p, cx0p, Wit, Wot, bi, hbi, bo, hbo,
                                            G12t, bvec, (float)N);
  // out = z @ G12 + bvec
  k_bgemm<<<dim3(N / 32, 2), blk, 0, stream>>>(B1p, G12t, out, nullptr, bvec, N, Hdim, 0, nullptr);
}

// Round 14
// 251.790 us; speedup vs baseline: 1.1593x; 1.1593x over previous
//
#include <hip/hip_runtime.h>
#include <hip/hip_bf16.h>
#include <math.h>

#define Hdim 128
#define NBq 8
#define SIq 16
#define LDP 136   // LDS row pitch (bf16 elems) for 128x128 fixup tiles
#define SKX 64    // split-K factor for xty2m

typedef __attribute__((ext_vector_type(8))) short short8x;
typedef __attribute__((ext_vector_type(8))) _Float16 half8x;
typedef __attribute__((ext_vector_type(4))) float f32x4;
typedef __attribute__((ext_vector_type(4))) unsigned short ushort4x;
typedef __attribute__((ext_vector_type(2))) _Float16 half2x;

__device__ inline unsigned short f2b(float f) {
  unsigned int u = __float_as_uint(f);
  return (unsigned short)((u + 0x7fffu + ((u >> 16) & 1u)) >> 16);   // RNE
}
__device__ inline unsigned int pack2(float lo, float hi) {
  return (unsigned int)f2b(lo) | ((unsigned int)f2b(hi) << 16);
}
__device__ inline unsigned short f2h(float f) {
  _Float16 h = (_Float16)f;
  unsigned short u;
  __builtin_memcpy(&u, &h, 2);
  return u;
}
__device__ inline half2x u2h(unsigned int u) {
  union { unsigned int u; half2x h; } v;
  v.u = u;
  return v.h;
}
__device__ inline float b2f(unsigned short u) {
  return __uint_as_float(((unsigned int)u) << 16);
}

// ---------------- fused preprocessing: gather | W-bdd transpose (f16) | dense-W transpose | dst histogram ----------------
__global__ __launch_bounds__(256) void k_pre(
    const float* __restrict__ emb, const int* __restrict__ ids, float* __restrict__ x0,
    unsigned short* __restrict__ x0h, unsigned short* __restrict__ x0t, int Nn,
    const float* __restrict__ W0, unsigned short* __restrict__ Wt0,
    const float* __restrict__ W1, unsigned short* __restrict__ Wt1, int w0elems,
    const float* __restrict__ l0, const float* __restrict__ l1,
    const float* __restrict__ Wi, const float* __restrict__ Wo, const float* __restrict__ Wz,
    unsigned short* __restrict__ l0t, unsigned short* __restrict__ l1t,
    unsigned short* __restrict__ Wit, unsigned short* __restrict__ Wot,
    unsigned short* __restrict__ Wzt,
    const int* __restrict__ dst, int* __restrict__ cnt, int E,
    int b1, int b2, int b3) {
  int bx = blockIdx.x, t = threadIdx.x;
  if (bx < b1) {
    int idx = bx * 256 + t;
    int n = idx >> 5, c4 = idx & 31;
    int s = ids[n];
    float4 v = ((const float4*)emb)[(size_t)s * 32 + c4];
    ((float4*)x0)[(size_t)n * 32 + c4] = v;
    ushort4x h;
    h.x = f2h(v.x); h.y = f2h(v.y); h.z = f2h(v.z); h.w = f2h(v.w);
    ((ushort4x*)x0h)[(size_t)n * 32 + c4] = h;
    int c0 = c4 * 4;
    x0t[(size_t)(c0 + 0) * Nn + n] = h.x;
    x0t[(size_t)(c0 + 1) * Nn + n] = h.y;
    x0t[(size_t)(c0 + 2) * Nn + n] = h.z;
    x0t[(size_t)(c0 + 3) * Nn + n] = h.w;
  } else if (bx < b2) {
    int idx = (bx - b1) * 256 + t;
    const float* W = (idx < w0elems) ? W0 : W1;
    unsigned short* Wt = (idx < w0elems) ? Wt0 : Wt1;
    int local = (idx < w0elems) ? idx : idx - w0elems;
    int rb = local >> 8, io = local & 255;
    int i = io >> 4, o = io & 15;
    Wt[(size_t)rb * 256 + o * 16 + i] = f2h(W[(size_t)rb * 256 + i * 16 + o]);   // f16 for v_dot2
  } else if (bx < b3) {
    int idx = (bx - b2) * 256 + t;
    if (idx < 65536) {
      int w = idx >> 14, local = idx & 16383;
      const float* in = (w == 0) ? l0 : (w == 1) ? l1 : (w == 2) ? Wi : Wo;
      unsigned short* out = (w == 0) ? l0t : (w == 1) ? l1t : (w == 2) ? Wit : Wot;
      int n = local >> 7, k = local & 127;
      out[local] = f2b(in[k * 128 + n]);
    } else {
      int local = idx - 65536;
      int n = local >> 7, k = local & 127;
      Wzt[local] = f2b(Wz[k * 256 + n]);
    }
  } else {
    int e = (bx - b3) * 256 + t;
    if (e < E) atomicAdd(&cnt[dst[e]], 1);
  }
}

// ---------------- dst CSR: scan / scatter-permute ----------------
__global__ __launch_bounds__(1024) void k_scan(const int* __restrict__ cnt,
                                               int* __restrict__ off,
                                               int* __restrict__ cur, int N, int E) {
  __shared__ int part[1024];
  int t = threadIdx.x;
  int ipt = N / 1024;
  int base = t * ipt;
  int loc[8];
  int s = 0;
  for (int i = 0; i < ipt; ++i) { loc[i] = s; s += cnt[base + i]; }
  part[t] = s;
  __syncthreads();
  for (int d = 1; d < 1024; d <<= 1) {
    int v = part[t];
    int add = (t >= d) ? part[t - d] : 0;
    __syncthreads();
    part[t] = v + add;
    __syncthreads();
  }
  int pre = (t == 0) ? 0 : part[t - 1];
  for (int i = 0; i < ipt; ++i) {
    int o = pre + loc[i];
    off[base + i] = o;
    cur[base + i] = o;
  }
  if (t == 0) off[N] = E;
}

__global__ void k_scatter(const int* __restrict__ src, const int* __restrict__ dst,
                          const int* __restrict__ et, const float* __restrict__ norm,
                          int* __restrict__ cur, int4* __restrict__ pedge, int E) {
  int e = blockIdx.x * blockDim.x + threadIdx.x;
  if (e >= E) return;
  int p = atomicAdd(&cur[dst[e]], 1);
  pedge[p] = make_int4(src[e], et[e], __float_as_int(norm[e]), 0);
}

// ---------------- segment-reduce edge aggregation, f16 x / f16 W, v_dot2 ----------------
__global__ __launch_bounds__(128) void k_edge(
    const unsigned short* __restrict__ xh, const unsigned short* __restrict__ Wt,
    const int* __restrict__ off, const int4* __restrict__ pedge,
    float* __restrict__ agg) {
  int n = blockIdx.x;
  int f = threadIdx.x;
  int b = f >> 4, o = f & 15;
  int j0 = off[n], j1 = off[n + 1];
  float acc = 0.f;
#pragma unroll 2
  for (int j = j0; j < j1; ++j) {
    int4 meta = pedge[j];
    int s = meta.x;
    int r = meta.y;
    float nv = __int_as_float(meta.z);
    const uint4* xp = (const uint4*)(xh + (size_t)s * Hdim + b * SIq);
    const uint4* wp = (const uint4*)(Wt + ((size_t)r * NBq + b) * 256 + o * SIq);
    uint4 xa = xp[0], xc = xp[1];
    uint4 wa = wp[0], wc = wp[1];
#if __has_builtin(__builtin_amdgcn_fdot2)
    float d0 = 0.f, d1 = 0.f;
    d0 = __builtin_amdgcn_fdot2(u2h(xa.x), u2h(wa.x), d0, false);
    d1 = __builtin_amdgcn_fdot2(u2h(xa.y), u2h(wa.y), d1, false);
    d0 = __builtin_amdgcn_fdot2(u2h(xa.z), u2h(wa.z), d0, false);
    d1 = __builtin_amdgcn_fdot2(u2h(xa.w), u2h(wa.w), d1, false);
    d0 = __builtin_amdgcn_fdot2(u2h(xc.x), u2h(wc.x), d0, false);
    d1 = __builtin_amdgcn_fdot2(u2h(xc.y), u2h(wc.y), d1, false);
    d0 = __builtin_amdgcn_fdot2(u2h(xc.z), u2h(wc.z), d0, false);
    d1 = __builtin_amdgcn_fdot2(u2h(xc.w), u2h(wc.w), d1, false);
    acc = fmaf(d0 + d1, nv, acc);
#else
    float d = 0.f;
    unsigned int xu[8] = {xa.x, xa.y, xa.z, xa.w, xc.x, xc.y, xc.z, xc.w};
    unsigned int wu[8] = {wa.x, wa.y, wa.z, wa.w, wc.x, wc.y, wc.z, wc.w};
#pragma unroll
    for (int k = 0; k < 8; ++k) {
      half2x xv = u2h(xu[k]), wv = u2h(wu[k]);
      d += (float)xv.x * (float)wv.x + (float)xv.y * (float)wv.y;
    }
    acc = fmaf(d, nv, acc);
#endif
  }
  agg[(size_t)n * Hdim + f] = acc;
}

// ---------------- MFMA bf16 GEMM: C[M,128] = A[M,128]@B + addm + bias + relu ----------------
__global__ __launch_bounds__(256) void k_bgemm(
    const float* __restrict__ A, const unsigned short* __restrict__ Bt,
    float* __restrict__ C,
    const float* __restrict__ addm, const float* __restrict__ bias,
    int M, int Nc, int relu, unsigned short* __restrict__ Ch) {
  __shared__ unsigned short Al[32][136];
  __shared__ unsigned short Bl[64][136];
  int t = threadIdx.x;
  int bm = blockIdx.x * 32, bn = blockIdx.y * 64;
  {
    int r = t >> 3, c0 = (t & 7) << 4;
    const float4* ap = (const float4*)(A + (size_t)(bm + r) * Hdim + c0);
    float4 a0 = ap[0], a1 = ap[1], a2 = ap[2], a3 = ap[3];
    uint4 p0 = { pack2(a0.x, a0.y), pack2(a0.z, a0.w), pack2(a1.x, a1.y), pack2(a1.z, a1.w) };
    uint4 p1 = { pack2(a2.x, a2.y), pack2(a2.z, a2.w), pack2(a3.x, a3.y), pack2(a3.z, a3.w) };
    *(uint4*)&Al[r][c0]     = p0;
    *(uint4*)&Al[r][c0 + 8] = p1;
  }
  {
    int n = t >> 2, k0 = (t & 3) << 5;
    const uint4* bp = (const uint4*)(Bt + (size_t)(bn + n) * Hdim + k0);
    uint4 b0 = bp[0], b1 = bp[1], b2 = bp[2], b3 = bp[3];
    *(uint4*)&Bl[n][k0]      = b0;
    *(uint4*)&Bl[n][k0 + 8]  = b1;
    *(uint4*)&Bl[n][k0 + 16] = b2;
    *(uint4*)&Bl[n][k0 + 24] = b3;
  }
  __syncthreads();
  int wv = t >> 6, ln = t & 63;
  int mt = wv & 1;
  int nt0 = (wv >> 1) << 1;
  int lm = ln & 15, lk = ln >> 4;
  f32x4 acc0 = {0.f, 0.f, 0.f, 0.f}, acc1 = {0.f, 0.f, 0.f, 0.f};
#pragma unroll
  for (int ks = 0; ks < 4; ++ks) {
    short8x af = *(const short8x*)&Al[mt * 16 + lm][ks * 32 + lk * 8];
    short8x bf0 = *(const short8x*)&Bl[nt0 * 16 + lm][ks * 32 + lk * 8];
    short8x bf1 = *(const short8x*)&Bl[(nt0 + 1) * 16 + lm][ks * 32 + lk * 8];
    acc0 = __builtin_amdgcn_mfma_f32_16x16x32_bf16(af, bf0, acc0, 0, 0, 0);
    acc1 = __builtin_amdgcn_mfma_f32_16x16x32_bf16(af, bf1, acc1, 0, 0, 0);
  }
  int gcol0 = bn + nt0 * 16 + lm;
  int gcol1 = gcol0 + 16;
  float b0v = bias ? bias[gcol0] : 0.f;
  float b1v = bias ? bias[gcol1] : 0.f;
#pragma unroll
  for (int reg = 0; reg < 4; ++reg) {
    int grow = bm + mt * 16 + lk * 4 + reg;
    size_t o0 = (size_t)grow * Nc + gcol0;
    size_t o1 = (size_t)grow * Nc + gcol1;
    float v0 = acc0[reg] + b0v;
    float v1 = acc1[reg] + b1v;
    if (addm) { v0 += addm[o0]; v1 += addm[o1]; }
    if (relu) { v0 = fmaxf(v0, 0.f); v1 = fmaxf(v1, 0.f); }
    C[o0] = v0;
    C[o1] = v1;
    if (Ch) { Ch[o0] = f2h(v0); Ch[o1] = f2h(v1); }
  }
}

// ---------------- MFMA bf16 zml GEMM fused with reparameterization (+ f16 Z^T emit, SP zeroing) ----------------
__global__ __launch_bounds__(256) void k_bgemm_z(
    const float* __restrict__ A, const unsigned short* __restrict__ Wzt,
    const float* __restrict__ bz, const float* __restrict__ eps,
    float* __restrict__ Z, int M, int Nn,
    unsigned short* __restrict__ Zth, float* __restrict__ gz) {
  __shared__ unsigned short Al[32][136];
  __shared__ unsigned short Bm[64][136];
  __shared__ unsigned short Bl[64][136];
  int t = threadIdx.x;
  int bm = blockIdx.x * 32, bn = blockIdx.y * 64;
  if (gz) {   // zero SP + s1 + cx0 (33024 floats = 8256 float4) distributed over the 512 blocks
    int idx = (blockIdx.x * 2 + blockIdx.y) * 256 + t;
    if (idx < 8256) ((float4*)gz)[idx] = make_float4(0.f, 0.f, 0.f, 0.f);
  }
  {
    int r = t >> 3, c0 = (t & 7) << 4;
    const float4* ap = (const float4*)(A + (size_t)(bm + r) * Hdim + c0);
    float4 a0 = ap[0], a1 = ap[1], a2 = ap[2], a3 = ap[3];
    uint4 p0 = { pack2(a0.x, a0.y), pack2(a0.z, a0.w), pack2(a1.x, a1.y), pack2(a1.z, a1.w) };
    uint4 p1 = { pack2(a2.x, a2.y), pack2(a2.z, a2.w), pack2(a3.x, a3.y), pack2(a3.z, a3.w) };
    *(uint4*)&Al[r][c0]     = p0;
    *(uint4*)&Al[r][c0 + 8] = p1;
  }
  {
    int n = t >> 2, k0 = (t & 3) << 5;
    const uint4* mp = (const uint4*)(Wzt + (size_t)(bn + n) * Hdim + k0);
    const uint4* lp = (const uint4*)(Wzt + (size_t)(bn + 128 + n) * Hdim + k0);
    uint4 m0 = mp[0], m1 = mp[1], m2 = mp[2], m3 = mp[3];
    uint4 l0 = lp[0], l1 = lp[1], l2 = lp[2], l3 = lp[3];
    *(uint4*)&Bm[n][k0]      = m0; *(uint4*)&Bm[n][k0 + 8]  = m1;
    *(uint4*)&Bm[n][k0 + 16] = m2; *(uint4*)&Bm[n][k0 + 24] = m3;
    *(uint4*)&Bl[n][k0]      = l0; *(uint4*)&Bl[n][k0 + 8]  = l1;
    *(uint4*)&Bl[n][k0 + 16] = l2; *(uint4*)&Bl[n][k0 + 24] = l3;
  }
  __syncthreads();
  int wv = t >> 6, ln = t & 63;
  int mt = wv & 1;
  int nt0 = (wv >> 1) << 1;
  int lm = ln & 15, lk = ln >> 4;
  f32x4 am0 = {0,0,0,0}, am1 = {0,0,0,0}, al0 = {0,0,0,0}, al1 = {0,0,0,0};
#pragma unroll
  for (int ks = 0; ks < 4; ++ks) {
    short8x af = *(const short8x*)&Al[mt * 16 + lm][ks * 32 + lk * 8];
    short8x bm0 = *(const short8x*)&Bm[nt0 * 16 + lm][ks * 32 + lk * 8];
    short8x bm1 = *(const short8x*)&Bm[(nt0 + 1) * 16 + lm][ks * 32 + lk * 8];
    short8x bl0 = *(const short8x*)&Bl[nt0 * 16 + lm][ks * 32 + lk * 8];
    short8x bl1 = *(const short8x*)&Bl[(nt0 + 1) * 16 + lm][ks * 32 + lk * 8];
    am0 = __builtin_amdgcn_mfma_f32_16x16x32_bf16(af, bm0, am0, 0, 0, 0);
    am1 = __builtin_amdgcn_mfma_f32_16x16x32_bf16(af, bm1, am1, 0, 0, 0);
    al0 = __builtin_amdgcn_mfma_f32_16x16x32_bf16(af, bl0, al0, 0, 0, 0);
    al1 = __builtin_amdgcn_mfma_f32_16x16x32_bf16(af, bl1, al1, 0, 0, 0);
  }
  int gcol0 = bn + nt0 * 16 + lm;
  int gcol1 = gcol0 + 16;
  float bm0v = bz[gcol0], bm1v = bz[gcol1];
  float bl0v = bz[128 + gcol0], bl1v = bz[128 + gcol1];
#pragma unroll
  for (int reg = 0; reg < 4; ++reg) {
    int grow = bm + mt * 16 + lk * 4 + reg;
    size_t o0 = (size_t)grow * Hdim + gcol0;
    size_t o1 = (size_t)grow * Hdim + gcol1;
    float v0 = am0[reg] + bm0v + expf(al0[reg] + bl0v) * eps[o0];
    float v1 = am1[reg] + bm1v + expf(al1[reg] + bl1v) * eps[o1];
    Z[o0] = v0;
    Z[o1] = v1;
    Zth[(size_t)gcol0 * Nn + grow] = f2h(v0);
    Zth[(size_t)gcol1 * Nn + grow] = f2h(v1);
  }
}

// ---------------- MFMA f16 split-K: SP += Zt-chunk^T outer products (atomic); + colsums ----------------
// Zt/X0t are [128][N] f16 (feature-major), so MFMA K (node index) is contiguous.
// Partials accumulate directly into SP via atomicAdd (32K addresses x 64
// contenders -- benign), removing the separate k_red dispatch.
__global__ __launch_bounds__(256) void k_xty2m(
    const unsigned short* __restrict__ Zt, const unsigned short* __restrict__ X0t,
    float* __restrict__ SP, float* __restrict__ s1, float* __restrict__ cx0, int N) {
  int kc = blockIdx.x, yt = blockIdx.y;
  int t = threadIdx.x;
  int KC = N / SKX;            // 128
  int k0 = kc * KC;
  if (yt == 4) {               // colsum blocks: s1 = colsum Z, cx0 = colsum X0
    int c = t & 127;
    const unsigned short* row = ((t >> 7) ? X0t : Zt) + (size_t)c * N + k0;
    float acc = 0.f;
    for (int i = 0; i < KC; i += 8) {
      uint4 v = *(const uint4*)(row + i);
      half2x a0 = u2h(v.x), a1 = u2h(v.y), a2 = u2h(v.z), a3 = u2h(v.w);
      acc += (float)a0.x + (float)a0.y + (float)a1.x + (float)a1.y
           + (float)a2.x + (float)a2.y + (float)a3.x + (float)a3.y;
    }
    atomicAdd(((t >> 7) ? cx0 : s1) + c, acc);
    return;
  }
  __shared__ unsigned short Asl[128][72];
  __shared__ unsigned short Bsl[64][72];
  int wv = t >> 6, ln = t & 63, lm = ln & 15, lk = ln >> 4;
  f32x4 acc[8];
#pragma unroll
  for (int i = 0; i < 8; ++i) acc[i] = (f32x4){0.f, 0.f, 0.f, 0.f};
  for (int ch = 0; ch < KC; ch += 64) {
    {   // stage A: all 128 features, 64 nodes
      int r = t >> 1, s = (t & 1) * 32;
      const uint4* gp = (const uint4*)(Zt + (size_t)r * N + k0 + ch + s);
      uint4 v0 = gp[0], v1 = gp[1], v2 = gp[2], v3 = gp[3];
      *(uint4*)&Asl[r][s]      = v0;
      *(uint4*)&Asl[r][s + 8]  = v1;
      *(uint4*)&Asl[r][s + 16] = v2;
      *(uint4*)&Asl[r][s + 24] = v3;
    }
    if (t < 128) {   // stage B: 64 rows of [Zt;X0t] for this col quarter
      int n = t >> 1, s = (t & 1) * 32;
      int yn = yt * 64 + n;
      const unsigned short* Sb = (yn < 128) ? (Zt + (size_t)yn * N)
                                            : (X0t + (size_t)(yn - 128) * N);
      const uint4* gp = (const uint4*)(Sb + k0 + ch + s);
      uint4 v0 = gp[0], v1 = gp[1], v2 = gp[2], v3 = gp[3];
      *(uint4*)&Bsl[n][s]      = v0;
      *(uint4*)&Bsl[n][s + 8]  = v1;
      *(uint4*)&Bsl[n][s + 16] = v2;
      *(uint4*)&Bsl[n][s + 24] = v3;
    }
    __syncthreads();
#pragma unroll
    for (int ks = 0; ks < 2; ++ks) {
      half8x bf = *(const half8x*)&Bsl[wv * 16 + lm][ks * 32 + lk * 8];
#pragma unroll
      for (int mi = 0; mi < 8; ++mi) {
        half8x af = *(const half8x*)&Asl[mi * 16 + lm][ks * 32 + lk * 8];
        acc[mi] = __builtin_amdgcn_mfma_f32_16x16x32_f16(af, bf, acc[mi], 0, 0, 0);
      }
    }
    __syncthreads();
  }
  int gcol = yt * 64 + wv * 16 + lm;
#pragma unroll
  for (int mi = 0; mi < 8; ++mi)
#pragma unroll
    for (int rg = 0; rg < 4; ++rg)
      atomicAdd(&SP[(size_t)(mi * 16 + lk * 4 + rg) * 256 + gcol], acc[mi][rg]);
}

// ---------------- single-block on-chip fixup: six 128^3 MFMA matmuls, ALL intermediates in LDS ----------------
__device__ inline void stage_f32(unsigned short* dst, const float* __restrict__ src,
                                 int ldF, int t) {
#pragma unroll
  for (int it = 0; it < 2; ++it) {
    int id = it * 1024 + t; int row = id >> 4, ch = id & 15;
    const float4* gp = (const float4*)(src + (size_t)row * ldF) + ch * 2;
    float4 u = gp[0], v = gp[1];
    uint4 pk = { pack2(u.x, u.y), pack2(u.z, u.w), pack2(v.x, v.y), pack2(v.z, v.w) };
    *(uint4*)&dst[row * LDP + ch * 8] = pk;
  }
}
__device__ inline void stage_b16(unsigned short* dst, const unsigned short* __restrict__ src,
                                 int t) {
#pragma unroll
  for (int it = 0; it < 2; ++it) {
    int id = it * 1024 + t; int row = id >> 4, ch = id & 15;
    *(uint4*)&dst[row * LDP + ch * 8] = ((const uint4*)(src + (size_t)row * 128))[ch];
  }
}
// 16 waves: wave (wr,wc) computes 32x32 output tile at (wr*32, wc*32)
__device__ inline void mm128(const unsigned short* A, const unsigned short* B,
                             f32x4 (&Cc)[2][2], int wr, int wc, int lm, int lk) {
#pragma unroll
  for (int ks = 0; ks < 4; ++ks) {
    short8x af0 = *(const short8x*)&A[(wr * 32 + lm) * LDP + ks * 32 + lk * 8];
    short8x af1 = *(const short8x*)&A[(wr * 32 + 16 + lm) * LDP + ks * 32 + lk * 8];
    short8x bf0 = *(const short8x*)&B[(wc * 32 + lm) * LDP + ks * 32 + lk * 8];
    short8x bf1 = *(const short8x*)&B[(wc * 32 + 16 + lm) * LDP + ks * 32 + lk * 8];
    Cc[0][0] = __builtin_amdgcn_mfma_f32_16x16x32_bf16(af0, bf0, Cc[0][0], 0, 0, 0);
    Cc[0][1] = __builtin_amdgcn_mfma_f32_16x16x32_bf16(af0, bf1, Cc[0][1], 0, 0, 0);
    Cc[1][0] = __builtin_amdgcn_mfma_f32_16x16x32_bf16(af1, bf0, Cc[1][0], 0, 0, 0);
    Cc[1][1] = __builtin_amdgcn_mfma_f32_16x16x32_bf16(af1, bf1, Cc[1][1], 0, 0, 0);
  }
}
#define ZEROC {                                           \
  _Pragma("unroll") for (int mi = 0; mi < 2; ++mi)        \
  _Pragma("unroll") for (int ni = 0; ni < 2; ++ni)        \
    C[mi][ni] = (f32x4){0.f, 0.f, 0.f, 0.f}; }

__global__ __launch_bounds__(1024) void k_fix(
    const float* __restrict__ SP, const float* __restrict__ s1g,
    const float* __restrict__ cx0g,
    const unsigned short* __restrict__ Wit, const unsigned short* __restrict__ Wot,
    const float* __restrict__ bi, const float* __restrict__ hbi,
    const float* __restrict__ bo, const float* __restrict__ hbo,
    unsigned short* __restrict__ G12t, float* __restrict__ bvec, float Nf) {
  __shared__ unsigned short T0[128 * LDP];
  __shared__ unsigned short T1[128 * LDP];
  __shared__ unsigned short T2[128 * LDP];
  __shared__ unsigned short T3[128 * LDP];
  __shared__ float s1l[128], tl[128], s2l[128], cxl[128], bil[128], bol[128], hl[128];
  int t = threadIdx.x;
  int wv = t >> 6, ln = t & 63, lm = ln & 15, lk = ln >> 4;
  int wr = wv >> 2, wc = wv & 3;
  if (t < 128) {
    s1l[t] = s1g[t]; cxl[t] = cx0g[t]; bil[t] = bi[t]; bol[t] = bo[t]; hl[t] = hbi[t];
  }
  stage_f32(T0, SP, 256, t);     // S1
  stage_b16(T1, Wit, t);         // Wi
  __syncthreads();
  f32x4 C[2][2];
  // ph1: G1 = S1 @ Wi + s1 (x) bi + P1 ; G1 -> T2, G1^T -> T3
  ZEROC; mm128(T0, T1, C, wr, wc, lm, lk);
#pragma unroll
  for (int mi = 0; mi < 2; ++mi)
#pragma unroll
  for (int ni = 0; ni < 2; ++ni) {
    int gcol = wc * 32 + ni * 16 + lm;
    int g0 = wr * 32 + mi * 16 + lk * 4;
    ushort4x pk;
#pragma unroll
    for (int rg = 0; rg < 4; ++rg) {
      int grow = g0 + rg;
      float v = C[mi][ni][rg] + s1l[grow] * bil[gcol] + SP[(size_t)grow * 256 + 128 + gcol];
      unsigned short hv = f2b(v);
      T2[grow * LDP + gcol] = hv;
      pk[rg] = hv;
    }
    *(ushort4x*)&T3[gcol * LDP + g0] = pk;
  }
  __syncthreads();
  // ph2: tl = G1^T s1 ; s2 = tl + N*hbi
  {
    int row = t >> 3, seg = t & 7;
    const unsigned short* gr = T3 + row * LDP + seg * 16;
    float a2 = 0.f;
#pragma unroll
    for (int i = 0; i < 16; ++i) a2 += b2f(gr[i]) * s1l[seg * 16 + i];
    a2 += __shfl_xor(a2, 1);
    a2 += __shfl_xor(a2, 2);
    a2 += __shfl_xor(a2, 4);
    if (seg == 0) { tl[row] = a2; s2l[row] = a2 + Nf * hl[row]; }
  }
  __syncthreads();
  // ph3: A2 = G1^T @ S1 -> T1 ; stage P1^T -> T0
  ZEROC; mm128(T3, T0, C, wr, wc, lm, lk);
  __syncthreads();
#pragma unroll
  for (int mi = 0; mi < 2; ++mi)
#pragma unroll
  for (int ni = 0; ni < 2; ++ni) {
    int gcol = wc * 32 + ni * 16 + lm;
    int g0 = wr * 32 + mi * 16 + lk * 4;
#pragma unroll
    for (int rg = 0; rg < 4; ++rg)
      T1[(g0 + rg) * LDP + gcol] = f2b(C[mi][ni][rg]);
  }
  {
#pragma unroll
    for (int it = 0; it < 2; ++it) {
      int id = it * 1024 + t; int row = id >> 4, c0 = (id & 15) * 8;
      const float4* gp = (const float4*)(SP + (size_t)row * 256 + 128 + c0);
      float4 u = gp[0], v2 = gp[1];
      float vals[8] = {u.x, u.y, u.z, u.w, v2.x, v2.y, v2.z, v2.w};
#pragma unroll
      for (int q = 0; q < 8; ++q) T0[(c0 + q) * LDP + row] = f2b(vals[q]);
    }
  }
  __syncthreads();
  // ph4: P2 = G1^T @ P1 + hbi (x) cx0 -> T0
  ZEROC; mm128(T3, T0, C, wr, wc, lm, lk);
  __syncthreads();
#pragma unroll
  for (int mi = 0; mi < 2; ++mi)
#pragma unroll
  for (int ni = 0; ni < 2; ++ni) {
    int gcol = wc * 32 + ni * 16 + lm;
    int g0 = wr * 32 + mi * 16 + lk * 4;
#pragma unroll
    for (int rg = 0; rg < 4; ++rg) {
      int grow = g0 + rg;
      T0[grow * LDP + gcol] = f2b(C[mi][ni][rg] + hl[grow] * cxl[gcol]);
    }
  }
  __syncthreads();
  // ph5: S2 = A2 @ G1 + rank-1 terms -> T1 ; stage Wo -> T3
  ZEROC; mm128(T1, T3, C, wr, wc, lm, lk);
  __syncthreads();
#pragma unroll
  for (int mi = 0; mi < 2; ++mi)
#pragma unroll
  for (int ni = 0; ni < 2; ++ni) {
    int gcol = wc * 32 + ni * 16 + lm;
    int g0 = wr * 32 + mi * 16 + lk * 4;
#pragma unroll
    for (int rg = 0; rg < 4; ++rg) {
      int grow = g0 + rg;
      float v = C[mi][ni][rg] + tl[grow] * hl[gcol] + hl[grow] * tl[gcol]
              + Nf * hl[grow] * hl[gcol];
      T1[grow * LDP + gcol] = f2b(v);
    }
  }
  stage_b16(T3, Wot, t);
  __syncthreads();
  // ph6: G2 = S2 @ Wo + s2 (x) bo + P2 -> G2^T in T0
  ZEROC; mm128(T1, T3, C, wr, wc, lm, lk);
  float g2v[2][2][4];
#pragma unroll
  for (int mi = 0; mi < 2; ++mi)
#pragma unroll
  for (int ni = 0; ni < 2; ++ni) {
    int gcol = wc * 32 + ni * 16 + lm;
    int g0 = wr * 32 + mi * 16 + lk * 4;
#pragma unroll
    for (int rg = 0; rg < 4; ++rg) {
      int grow = g0 + rg;
      g2v[mi][ni][rg] = C[mi][ni][rg] + s2l[grow] * bol[gcol]
                      + b2f(T0[grow * LDP + gcol]);
    }
  }
  __syncthreads();
#pragma unroll
  for (int mi = 0; mi < 2; ++mi)
#pragma unroll
  for (int ni = 0; ni < 2; ++ni) {
    int gcol = wc * 32 + ni * 16 + lm;
    int g0 = wr * 32 + mi * 16 + lk * 4;
    ushort4x pk;
#pragma unroll
    for (int rg = 0; rg < 4; ++rg) pk[rg] = f2b(g2v[mi][ni][rg]);
    *(ushort4x*)&T0[gcol * LDP + g0] = pk;
  }
  __syncthreads();
  // ph8: bvec
  {
    int row = t >> 3, seg = t & 7;
    const unsigned short* gr = T0 + row * LDP + seg * 16;
    float a2 = 0.f;
#pragma unroll
    for (int i = 0; i < 16; ++i) a2 += hl[seg * 16 + i] * b2f(gr[i]);
    a2 += __shfl_xor(a2, 1);
    a2 += __shfl_xor(a2, 2);
    a2 += __shfl_xor(a2, 4);
    if (seg == 0) bvec[row] = a2 + hbo[row];
  }
  // ph7: G12 = G1 @ G2 -> G12^T in T1 -> coalesced copy out
  ZEROC; mm128(T2, T0, C, wr, wc, lm, lk);
#pragma unroll
  for (int mi = 0; mi < 2; ++mi)
#pragma unroll
  for (int ni = 0; ni < 2; ++ni) {
    int gcol = wc * 32 + ni * 16 + lm;
    int g0 = wr * 32 + mi * 16 + lk * 4;
    ushort4x pk;
#pragma unroll
    for (int rg = 0; rg < 4; ++rg) pk[rg] = f2b(C[mi][ni][rg]);
    *(ushort4x*)&T1[gcol * LDP + g0] = pk;
  }
  __syncthreads();
#pragma unroll
  for (int it = 0; it < 2; ++it) {
    int id = it * 1024 + t; int row = id >> 4, ch = (id & 15) * 8;
    *(uint4*)&G12t[row * 128 + ch] = *(uint4*)&T1[row * LDP + ch];
  }
}

extern "C" void kernel_launch(void* const* d_in, const int* in_sizes, int n_in,
                              void* d_out, int out_size, void* d_ws, size_t ws_size,
                              hipStream_t stream) {
  const int*   node_ids = (const int*)d_in[0];
  const int*   src      = (const int*)d_in[1];
  const int*   dst      = (const int*)d_in[2];
  const int*   et       = (const int*)d_in[3];
  const float* norm     = (const float*)d_in[4];
  const float* eps      = (const float*)d_in[5];
  const float* emb      = (const float*)d_in[6];
  const float* W0       = (const float*)d_in[7];
  const float* loop0    = (const float*)d_in[8];
  const float* b0       = (const float*)d_in[9];
  const float* W1       = (const float*)d_in[10];
  const float* loop1    = (const float*)d_in[11];
  const float* b1       = (const float*)d_in[12];
  const float* Wz       = (const float*)d_in[13];
  const float* bz       = (const float*)d_in[14];
  const float* Wi       = (const float*)d_in[15];
  const float* bi       = (const float*)d_in[16];
  const float* hbi      = (const float*)d_in[17];
  const float* Wo       = (const float*)d_in[18];
  const float* bo       = (const float*)d_in[19];
  const float* hbo      = (const float*)d_in[20];
  float* out = (float*)d_out;

  const int N  = in_sizes[0];   // 8192
  const int E  = in_sizes[1];   // 131072
  const int RB = in_sizes[7] / (SIq * SIq);   // NREL * NBq = 720

  char* ws = (char*)d_ws;
  const size_t MB = 1u << 20;
  const size_t KB = 1u << 10;
  float* X0   = (float*)(ws + 0 * MB);
  float* B1p  = (float*)(ws + 4 * MB);      // h1, then z
  float* B2p  = (float*)(ws + 8 * MB);      // h2
  float* AGG  = (float*)(ws + 12 * MB);
  float* SPb  = (float*)(ws + 16 * MB);     // SP 128x256 f32 + s1 + cx0 (33024 floats)
  float* s1p  = SPb + 32768;
  float* cx0p = SPb + 32896;
  unsigned short* G12t = (unsigned short*)(ws + 16 * MB + 576 * KB);
  float* bvec = (float*)(ws + 16 * MB + 640 * KB);
  int*   offp = (int*)(ws + 17 * MB);
  int*   curp = (int*)(ws + 17 * MB + 128 * KB);
  int*   cntp = (int*)(ws + 17 * MB + 256 * KB);
  int4*  pedge = (int4*)(ws + 18 * MB);                              // 2 MB
  unsigned short* Wt0 = (unsigned short*)(ws + 20 * MB);             // 368 KB (f16)
  unsigned short* Wt1 = (unsigned short*)(ws + 20 * MB + 512 * KB);  // 368 KB (f16)
  unsigned short* l0t = (unsigned short*)(ws + 21 * MB);             // 32 KB
  unsigned short* l1t = (unsigned short*)(ws + 21 * MB + 64 * KB);
  unsigned short* Wit = (unsigned short*)(ws + 21 * MB + 128 * KB);
  unsigned short* Wot = (unsigned short*)(ws + 21 * MB + 192 * KB);
  unsigned short* Wzt = (unsigned short*)(ws + 21 * MB + 256 * KB);  // 64 KB
  unsigned short* X0H = (unsigned short*)(ws + 22 * MB);             // 2 MB (f16 x0, row-major)
  unsigned short* B1H = (unsigned short*)(ws + 24 * MB);             // 2 MB (f16 h1, row-major)
  unsigned short* Ztc = (unsigned short*)(ws + 26 * MB);             // 2 MB (f16 z, col-major)
  unsigned short* X0t = (unsigned short*)(ws + 28 * MB);             // 2 MB (f16 x0, col-major)

  dim3 blk(256);

  // ---- fused preprocessing ----
  const int w0elems = RB * 256;                      // 184320
  const int gB   = (N * 32) / 256;                   // 1024
  const int wtbB = (2 * w0elems + 255) / 256;        // 1440
  const int wttB = 98304 / 256;                      // 384
  const int histB = (E + 255) / 256;                 // 512
  const int b1s = gB, b2s = gB + wtbB, b3s = gB + wtbB + wttB;
  hipMemsetAsync(cntp, 0, (size_t)N * sizeof(int), stream);
  k_pre<<<dim3(b3s + histB), blk, 0, stream>>>(
      emb, node_ids, X0, X0H, X0t, N, W0, Wt0, W1, Wt1, w0elems,
      loop0, loop1, Wi, Wo, Wz, l0t, l1t, Wit, Wot, Wzt,
      dst, cntp, E, b1s, b2s, b3s);
  k_scan<<<dim3(1), dim3(1024), 0, stream>>>(cntp, offp, curp, N, E);
  k_scatter<<<dim3((E + 255) / 256), blk, 0, stream>>>(src, dst, et, norm, curp, pedge, E);

  // layer-0 edge aggregation (f16 x, f16 W, v_dot2)
  k_edge<<<dim3(N), dim3(128), 0, stream>>>(X0H, Wt0, offp, pedge, AGG);
  // h1 = relu(agg + b0 + x0@loop0); also emit f16 copy
  k_bgemm<<<dim3(N / 32, 2), blk, 0, stream>>>(X0, l0t, B1p, AGG, b0, N, Hdim, 1, B1H);
  // layer-1 edge aggregation
  k_edge<<<dim3(N), dim3(128), 0, stream>>>(B1H, Wt1, offp, pedge, AGG);
  // h2 = agg + b1 + h1@loop1
  k_bgemm<<<dim3(N / 32, 2), blk, 0, stream>>>(B1p, l1t, B2p, AGG, b1, N, Hdim, 0, nullptr);
  // z = mean + exp(log_std)*eps -> B1p, Ztc (f16 col-major); zero SP/s1/cx0
  k_bgemm_z<<<dim3(N / 32, 2), blk, 0, stream>>>(B2p, Wzt, bz, eps, B1p, N, N, Ztc, SPb);
  // SP += z^T [z | x0] (atomic split-K), + colsums
  k_xty2m<<<dim3(SKX, 5), blk, 0, stream>>>(Ztc, X0t, SPb, s1p, cx0p, N);
  // on-chip algebraic fixup -> G12 (bf16 Bt layout) + bvec
  k_fix<<<dim3(1), dim3(1024), 0, stream>>>(SPb, s1p, cx0p, Wit, Wot, bi, hbi, bo, hbo,
                                            G12t, bvec, (float)N);
  // out = z @ G12 + bvec
  k_bgemm<<<dim3(N / 32, 2), blk, 0, stream>>>(B1p, G12t, out, nullptr, bvec, N, Hdim, 0, nullptr);
}